// Round 2
// baseline (959.901 us; speedup 1.0000x reference)
//
#include <hip/hip_runtime.h>
#include <hip/hip_bf16.h>

// GCN block: 3 x { t = relu(h @ W^T); h' = A_coo @ t (per batch) }
// B=8, N=10000, D=64, E=160000.
//
// Layout decisions:
//  - gemm_relu: one wave per row of h (lane = output feature f).
//    W (64x64 f32, 16KB) lives in 64 VGPRs per lane (lane f holds W[f, 0..63]).
//    h row read via broadcast float4 loads (wave-uniform address).
//  - spmm: thread = (edge e, feature d); e is wave-uniform so the index loads
//    are broadcast. Loops over the 8 batches. Scatter via HW f32 atomics.
//  - h buffer ping-pongs through d_out (zeroed with hipMemsetAsync before each
//    scatter); t lives in d_ws (needs B*N*D*4 = 20.48 MB).

#define GCN_B 8
#define GCN_N 10000
#define GCN_D 64
#define GCN_E 160000

__global__ __launch_bounds__(256) void gemm_relu_kernel(
    const float* __restrict__ h,   // [BN, 64]
    const float* __restrict__ W,   // [64, 64] row-major; out[f] = sum_d h[d]*W[f*64+d]
    float* __restrict__ t,         // [BN, 64]
    int BN)
{
    const int f = threadIdx.x & 63;   // lane = output feature
    const int w = threadIdx.x >> 6;   // wave id within block (4 waves)

    // Cache W row f in registers: 16 x float4 = 64 floats.
    float4 wr[16];
    const float4* W4 = reinterpret_cast<const float4*>(W);
#pragma unroll
    for (int i = 0; i < 16; ++i) wr[i] = W4[f * 16 + i];

    for (int row = blockIdx.x * 4 + w; row < BN; row += gridDim.x * 4) {
        const float4* hp = reinterpret_cast<const float4*>(h + (size_t)row * 64);
        float acc = 0.0f;
#pragma unroll
        for (int i = 0; i < 16; ++i) {
            float4 hv = hp[i];   // wave-uniform address -> broadcast
            acc += hv.x * wr[i].x + hv.y * wr[i].y + hv.z * wr[i].z + hv.w * wr[i].w;
        }
        t[(size_t)row * 64 + f] = fmaxf(acc, 0.0f);
    }
}

__global__ __launch_bounds__(256) void spmm_kernel(
    const float* __restrict__ t,     // [B, N, 64]
    const float* __restrict__ vals,  // [E]
    const int* __restrict__ rows,    // [E]
    const int* __restrict__ cols,    // [E]
    float* __restrict__ out,         // [B, N, 64], pre-zeroed
    int N, int E)
{
    const int gid = blockIdx.x * 256 + threadIdx.x;
    const int e = gid >> 6;          // wave-uniform
    const int d = gid & 63;
    if (e >= E) return;

    const float v = vals[e];
    const int r = rows[e];
    const int c = cols[e];

#pragma unroll
    for (int b = 0; b < GCN_B; ++b) {
        const float tv = t[((size_t)b * N + c) * 64 + d];     // coalesced 256B gather
        unsafeAtomicAdd(&out[((size_t)b * N + r) * 64 + d], v * tv);
    }
}

extern "C" void kernel_launch(void* const* d_in, const int* in_sizes, int n_in,
                              void* d_out, int out_size, void* d_ws, size_t ws_size,
                              hipStream_t stream) {
    const float* x    = (const float*)d_in[0];
    const float* W0   = (const float*)d_in[1];
    const float* W1   = (const float*)d_in[2];
    const float* W2   = (const float*)d_in[3];
    const float* vals = (const float*)d_in[4];
    const int*   rows = (const int*)d_in[5];
    const int*   cols = (const int*)d_in[6];
    float* out = (float*)d_out;
    float* t   = (float*)d_ws;   // B*N*64 floats = 20.48 MB

    const int BN = GCN_B * GCN_N;
    const size_t out_bytes = (size_t)BN * GCN_D * sizeof(float);

    const int gemm_grid = 1280;                        // 5 blocks/CU, grid-stride
    const int spmm_grid = (GCN_E * GCN_D + 255) / 256; // 40000 blocks

    // ---- layer 1 ----
    gemm_relu_kernel<<<gemm_grid, 256, 0, stream>>>(x, W0, t, BN);
    hipMemsetAsync(out, 0, out_bytes, stream);
    spmm_kernel<<<spmm_grid, 256, 0, stream>>>(t, vals, rows, cols, out, GCN_N, GCN_E);

    // ---- layer 2 ----
    gemm_relu_kernel<<<gemm_grid, 256, 0, stream>>>(out, W1, t, BN);
    hipMemsetAsync(out, 0, out_bytes, stream);
    spmm_kernel<<<spmm_grid, 256, 0, stream>>>(t, vals, rows, cols, out, GCN_N, GCN_E);

    // ---- layer 3 ----
    gemm_relu_kernel<<<gemm_grid, 256, 0, stream>>>(out, W2, t, BN);
    hipMemsetAsync(out, 0, out_bytes, stream);
    spmm_kernel<<<spmm_grid, 256, 0, stream>>>(t, vals, rows, cols, out, GCN_N, GCN_E);
}

// Round 3
// 426.455 us; speedup vs baseline: 2.2509x; 2.2509x over previous
//
#include <hip/hip_runtime.h>
#include <hip/hip_bf16.h>

// GCN block: 3 x { t = relu(h @ W^T); h' = A_coo @ t (per batch) }
// B=8, N=10000, D=64, E=160000.
//
// Round 3: CSR-based gather SpMM (zero output atomics), ILP'd GEMM.
//  - Build CSR once per launch: histogram(rows) -> block scan -> scatter perm.
//    Reused by all 3 layers. ~2 MB extra workspace.
//  - spmm_csr: wave per output row, lane = feature d, 8 batch accumulators in
//    VGPRs. Gathers t[b,c,0..63] coalesced (256B); writes each output once.
//    Kills the 320 MB/dispatch HBM atomic write-through seen in round 2.
//  - gemm_relu: 4 rows per wave (4 independent FMA chains) to break the
//    64-deep dependency chain that made round 2's GEMM latency-bound.

#define GCN_B 8
#define GCN_N 10000
#define GCN_D 64
#define GCN_E 160000

// ---------------- GEMM + ReLU ----------------
__global__ __launch_bounds__(256) void gemm_relu_kernel(
    const float* __restrict__ h,   // [BN, 64]
    const float* __restrict__ W,   // [64, 64]; out[f] = sum_d h[d]*W[f*64+d]
    float* __restrict__ t,         // [BN, 64]
    int BN)
{
    const int f = threadIdx.x & 63;                       // lane = output feature
    const int wave = (blockIdx.x * 256 + threadIdx.x) >> 6;

    // W row f in 16 float4 registers.
    float4 wr[16];
    const float4* W4 = reinterpret_cast<const float4*>(W);
#pragma unroll
    for (int i = 0; i < 16; ++i) wr[i] = W4[f * 16 + i];

    const int r0 = wave * 4;                              // 4 rows per wave
    if (r0 >= BN) return;

    const float4* h0 = reinterpret_cast<const float4*>(h + (size_t)(r0 + 0) * 64);
    const float4* h1 = reinterpret_cast<const float4*>(h + (size_t)(r0 + 1) * 64);
    const float4* h2 = reinterpret_cast<const float4*>(h + (size_t)(r0 + 2) * 64);
    const float4* h3 = reinterpret_cast<const float4*>(h + (size_t)(r0 + 3) * 64);

    float a0 = 0.f, a1 = 0.f, a2 = 0.f, a3 = 0.f;
#pragma unroll
    for (int i = 0; i < 16; ++i) {
        float4 v0 = h0[i], v1 = h1[i], v2 = h2[i], v3 = h3[i];   // broadcast loads
        float4 w = wr[i];
        a0 += v0.x * w.x + v0.y * w.y + v0.z * w.z + v0.w * w.w;
        a1 += v1.x * w.x + v1.y * w.y + v1.z * w.z + v1.w * w.w;
        a2 += v2.x * w.x + v2.y * w.y + v2.z * w.z + v2.w * w.w;
        a3 += v3.x * w.x + v3.y * w.y + v3.z * w.z + v3.w * w.w;
    }
    t[(size_t)(r0 + 0) * 64 + f] = fmaxf(a0, 0.0f);
    t[(size_t)(r0 + 1) * 64 + f] = fmaxf(a1, 0.0f);
    t[(size_t)(r0 + 2) * 64 + f] = fmaxf(a2, 0.0f);
    t[(size_t)(r0 + 3) * 64 + f] = fmaxf(a3, 0.0f);
}

// ---------------- CSR build ----------------
__global__ __launch_bounds__(256) void hist_kernel(
    const int* __restrict__ rows, int* __restrict__ cnt, int E)
{
    int e = blockIdx.x * 256 + threadIdx.x;
    if (e < E) atomicAdd(&cnt[rows[e]], 1);
}

__global__ __launch_bounds__(256) void scan_kernel(
    const int* __restrict__ cnt, int* __restrict__ row_ptr, int* __restrict__ cur)
{
    __shared__ int part[256];
    const int tid = threadIdx.x;
    const int per = (GCN_N + 255) / 256;   // 40
    const int base = tid * per;

    int s = 0;
    for (int i = 0; i < per; ++i) {
        int idx = base + i;
        if (idx < GCN_N) s += cnt[idx];
    }
    part[tid] = s;
    __syncthreads();
    // inclusive Hillis-Steele scan of part[]
    for (int off = 1; off < 256; off <<= 1) {
        int add = (tid >= off) ? part[tid - off] : 0;
        __syncthreads();
        part[tid] += add;
        __syncthreads();
    }
    int run = part[tid] - s;               // exclusive prefix for this segment
    for (int i = 0; i < per; ++i) {
        int idx = base + i;
        if (idx < GCN_N) {
            row_ptr[idx] = run;
            cur[idx] = run;
            run += cnt[idx];
        }
    }
    if (tid == 0) row_ptr[GCN_N] = GCN_E;
}

__global__ __launch_bounds__(256) void scatter_kernel(
    const float* __restrict__ vals, const int* __restrict__ rows,
    const int* __restrict__ cols, int* __restrict__ cur,
    float* __restrict__ pval, int* __restrict__ pcol, int E)
{
    int e = blockIdx.x * 256 + threadIdx.x;
    if (e >= E) return;
    int pos = atomicAdd(&cur[rows[e]], 1);
    pval[pos] = vals[e];
    pcol[pos] = cols[e];
}

// ---------------- CSR SpMM (gather, no atomics) ----------------
__global__ __launch_bounds__(256) void spmm_csr_kernel(
    const float* __restrict__ t,       // [B, N, 64]
    const float* __restrict__ pval,    // [E] row-sorted
    const int* __restrict__ pcol,      // [E] row-sorted
    const int* __restrict__ row_ptr,   // [N+1]
    float* __restrict__ out)           // [B, N, 64]
{
    const int r = (blockIdx.x * 256 + threadIdx.x) >> 6;   // wave = output row
    const int d = threadIdx.x & 63;
    if (r >= GCN_N) return;

    const int beg = row_ptr[r];
    const int end = row_ptr[r + 1];

    float acc[GCN_B];
#pragma unroll
    for (int b = 0; b < GCN_B; ++b) acc[b] = 0.0f;

    for (int j = beg; j < end; ++j) {
        const float v = pval[j];                 // broadcast
        const int c = pcol[j];                   // broadcast
        const float* tp = t + (size_t)c * 64 + d;
#pragma unroll
        for (int b = 0; b < GCN_B; ++b)
            acc[b] += v * tp[(size_t)b * GCN_N * 64];   // coalesced 256B gathers
    }
#pragma unroll
    for (int b = 0; b < GCN_B; ++b)
        out[((size_t)b * GCN_N + r) * 64 + d] = acc[b];
}

// ---------------- round-2 fallback (atomic scatter) ----------------
__global__ __launch_bounds__(256) void spmm_atomic_kernel(
    const float* __restrict__ t, const float* __restrict__ vals,
    const int* __restrict__ rows, const int* __restrict__ cols,
    float* __restrict__ out, int N, int E)
{
    const int gid = blockIdx.x * 256 + threadIdx.x;
    const int e = gid >> 6;
    const int d = gid & 63;
    if (e >= E) return;
    const float v = vals[e];
    const int r = rows[e];
    const int c = cols[e];
#pragma unroll
    for (int b = 0; b < GCN_B; ++b) {
        const float tv = t[((size_t)b * N + c) * 64 + d];
        unsafeAtomicAdd(&out[((size_t)b * N + r) * 64 + d], v * tv);
    }
}

extern "C" void kernel_launch(void* const* d_in, const int* in_sizes, int n_in,
                              void* d_out, int out_size, void* d_ws, size_t ws_size,
                              hipStream_t stream) {
    const float* x    = (const float*)d_in[0];
    const float* W0   = (const float*)d_in[1];
    const float* W1   = (const float*)d_in[2];
    const float* W2   = (const float*)d_in[3];
    const float* vals = (const float*)d_in[4];
    const int*   rows = (const int*)d_in[5];
    const int*   cols = (const int*)d_in[6];
    float* out = (float*)d_out;

    const int BN = GCN_B * GCN_N;
    const size_t t_bytes = (size_t)BN * GCN_D * sizeof(float);   // 20,480,000

    char* ws = (char*)d_ws;
    float* t      = (float*)ws;                                  // 20,480,000 B
    size_t off = t_bytes;
    int*   row_ptr = (int*)(ws + off); off += ((GCN_N + 1) * 4 + 255) / 256 * 256;
    int*   cur     = (int*)(ws + off); off += (GCN_N * 4 + 255) / 256 * 256;
    int*   cnt     = (int*)(ws + off); off += (GCN_N * 4 + 255) / 256 * 256;
    float* pval    = (float*)(ws + off); off += GCN_E * 4;
    int*   pcol    = (int*)(ws + off); off += GCN_E * 4;
    const bool use_csr = (ws_size >= off);

    const int gemm_grid = BN / 4 / 4;            // 4 rows/wave, 4 waves/block = 5000
    const int edge_grid = (GCN_E + 255) / 256;   // 625
    const int spmm_grid = (GCN_N * 64 + 255) / 256; // 2500 (wave per row)

    if (use_csr) {
        // Build CSR once; reused by all 3 layers.
        hipMemsetAsync(cnt, 0, GCN_N * sizeof(int), stream);
        hist_kernel<<<edge_grid, 256, 0, stream>>>(rows, cnt, GCN_E);
        scan_kernel<<<1, 256, 0, stream>>>(cnt, row_ptr, cur);
        scatter_kernel<<<edge_grid, 256, 0, stream>>>(vals, rows, cols, cur, pval, pcol, GCN_E);

        gemm_relu_kernel<<<gemm_grid, 256, 0, stream>>>(x, W0, t, BN);
        spmm_csr_kernel<<<spmm_grid, 256, 0, stream>>>(t, pval, pcol, row_ptr, out);

        gemm_relu_kernel<<<gemm_grid, 256, 0, stream>>>(out, W1, t, BN);
        spmm_csr_kernel<<<spmm_grid, 256, 0, stream>>>(t, pval, pcol, row_ptr, out);

        gemm_relu_kernel<<<gemm_grid, 256, 0, stream>>>(out, W2, t, BN);
        spmm_csr_kernel<<<spmm_grid, 256, 0, stream>>>(t, pval, pcol, row_ptr, out);
    } else {
        const int spmm_grid_a = (GCN_E * GCN_D + 255) / 256;
        gemm_relu_kernel<<<gemm_grid, 256, 0, stream>>>(x, W0, t, BN);
        hipMemsetAsync(out, 0, t_bytes, stream);
        spmm_atomic_kernel<<<spmm_grid_a, 256, 0, stream>>>(t, vals, rows, cols, out, GCN_N, GCN_E);

        gemm_relu_kernel<<<gemm_grid, 256, 0, stream>>>(out, W1, t, BN);
        hipMemsetAsync(out, 0, t_bytes, stream);
        spmm_atomic_kernel<<<spmm_grid_a, 256, 0, stream>>>(t, vals, rows, cols, out, GCN_N, GCN_E);

        gemm_relu_kernel<<<gemm_grid, 256, 0, stream>>>(out, W2, t, BN);
        hipMemsetAsync(out, 0, t_bytes, stream);
        spmm_atomic_kernel<<<spmm_grid_a, 256, 0, stream>>>(t, vals, rows, cols, out, GCN_N, GCN_E);
    }
}

// Round 4
// 341.075 us; speedup vs baseline: 2.8143x; 1.2503x over previous
//
#include <hip/hip_runtime.h>
#include <hip/hip_bf16.h>

// GCN block: 3 x { t = relu(h @ W^T); h' = A_coo @ t (per batch) }
// B=8, N=10000, D=64, E=160000.
//
// Round 4:
//  - gemm_relu: grid-stride (W cached in 64 VGPRs ONCE per wave, amortized
//    over ~16 rows) + 4-row ILP per group. Round 3 loaded W per 4-row group
//    (20000 waves x 16 loads) and had no outer loop to pipeline -> 78us at
//    13% VALUBusy. This combines round-2 amortization with round-3 ILP.
//  - t layout transposed to [n][b][64]: SpMM gathers 2KB contiguous per edge
//    as 2 x dwordx4 per lane (was 8 scattered 256B loads). GEMM writes this
//    layout for free. Intermediate h ping-pongs through d_out in [n][b];
//    final SpMM writes proper [b][n][64].
//  - CSR build (hist/scan/scatter) unchanged from round 3.

#define GCN_B 8
#define GCN_N 10000
#define GCN_D 64
#define GCN_E 160000
#define GCN_BN (GCN_B * GCN_N)

// ---------------- GEMM + ReLU ----------------
// out rows are [n][b] flat: rid = n*8 + b. If permute_in, input row is b*N+n
// (layer 1 reads x in [b][n]); else input is already [n][b] flat.
__global__ __launch_bounds__(256) void gemm_relu_kernel(
    const float* __restrict__ h,
    const float* __restrict__ W,   // [64,64]; out[f] = sum_d h[d]*W[f*64+d]
    float* __restrict__ t,         // [N][B][64] flat
    int permute_in)
{
    const int f = threadIdx.x & 63;
    const int wid = (blockIdx.x * 256 + threadIdx.x) >> 6;
    const int nw = gridDim.x * 4;

    const float4* W4 = reinterpret_cast<const float4*>(W);
    float4 wr[16];
#pragma unroll
    for (int i = 0; i < 16; ++i) wr[i] = W4[f * 16 + i];

    for (int g = wid * 4; g < GCN_BN; g += nw * 4) {
        const float4* hp0;
        const float4* hp1;
        const float4* hp2;
        const float4* hp3;
        if (permute_in) {
            int n0 = (g + 0) >> 3, b0 = (g + 0) & 7;
            int n1 = (g + 1) >> 3, b1 = (g + 1) & 7;
            int n2 = (g + 2) >> 3, b2 = (g + 2) & 7;
            int n3 = (g + 3) >> 3, b3 = (g + 3) & 7;
            hp0 = reinterpret_cast<const float4*>(h + ((size_t)b0 * GCN_N + n0) * 64);
            hp1 = reinterpret_cast<const float4*>(h + ((size_t)b1 * GCN_N + n1) * 64);
            hp2 = reinterpret_cast<const float4*>(h + ((size_t)b2 * GCN_N + n2) * 64);
            hp3 = reinterpret_cast<const float4*>(h + ((size_t)b3 * GCN_N + n3) * 64);
        } else {
            hp0 = reinterpret_cast<const float4*>(h + (size_t)(g + 0) * 64);
            hp1 = reinterpret_cast<const float4*>(h + (size_t)(g + 1) * 64);
            hp2 = reinterpret_cast<const float4*>(h + (size_t)(g + 2) * 64);
            hp3 = reinterpret_cast<const float4*>(h + (size_t)(g + 3) * 64);
        }
        float a0 = 0.f, a1 = 0.f, a2 = 0.f, a3 = 0.f;
#pragma unroll
        for (int i = 0; i < 16; ++i) {
            float4 w = wr[i];
            float4 v0 = hp0[i], v1 = hp1[i], v2 = hp2[i], v3 = hp3[i];
            a0 += v0.x * w.x + v0.y * w.y + v0.z * w.z + v0.w * w.w;
            a1 += v1.x * w.x + v1.y * w.y + v1.z * w.z + v1.w * w.w;
            a2 += v2.x * w.x + v2.y * w.y + v2.z * w.z + v2.w * w.w;
            a3 += v3.x * w.x + v3.y * w.y + v3.z * w.z + v3.w * w.w;
        }
        t[(size_t)(g + 0) * 64 + f] = fmaxf(a0, 0.0f);
        t[(size_t)(g + 1) * 64 + f] = fmaxf(a1, 0.0f);
        t[(size_t)(g + 2) * 64 + f] = fmaxf(a2, 0.0f);
        t[(size_t)(g + 3) * 64 + f] = fmaxf(a3, 0.0f);
    }
}

// ---------------- CSR build ----------------
__global__ __launch_bounds__(256) void hist_kernel(
    const int* __restrict__ rows, int* __restrict__ cnt, int E)
{
    int e = blockIdx.x * 256 + threadIdx.x;
    if (e < E) atomicAdd(&cnt[rows[e]], 1);
}

__global__ __launch_bounds__(256) void scan_kernel(
    const int* __restrict__ cnt, int* __restrict__ row_ptr, int* __restrict__ cur)
{
    __shared__ int part[256];
    const int tid = threadIdx.x;
    const int per = (GCN_N + 255) / 256;   // 40
    const int base = tid * per;

    int s = 0;
    for (int i = 0; i < per; ++i) {
        int idx = base + i;
        if (idx < GCN_N) s += cnt[idx];
    }
    part[tid] = s;
    __syncthreads();
    for (int off = 1; off < 256; off <<= 1) {
        int add = (tid >= off) ? part[tid - off] : 0;
        __syncthreads();
        part[tid] += add;
        __syncthreads();
    }
    int run = part[tid] - s;
    for (int i = 0; i < per; ++i) {
        int idx = base + i;
        if (idx < GCN_N) {
            row_ptr[idx] = run;
            cur[idx] = run;
            run += cnt[idx];
        }
    }
    if (tid == 0) row_ptr[GCN_N] = GCN_E;
}

__global__ __launch_bounds__(256) void scatter_kernel(
    const float* __restrict__ vals, const int* __restrict__ rows,
    const int* __restrict__ cols, int* __restrict__ cur,
    float* __restrict__ pval, int* __restrict__ pcol, int E)
{
    int e = blockIdx.x * 256 + threadIdx.x;
    if (e >= E) return;
    int pos = atomicAdd(&cur[rows[e]], 1);
    pval[pos] = vals[e];
    pcol[pos] = cols[e];
}

// ---------------- CSR SpMM (gather, no atomics) ----------------
// t is [N][B*64] = [N][512] floats = [N][128] float4. Lane holds float4
// chunks q=lane and q=64+lane of the 512-float row: b = q>>4, d = (q&15)*4.
__global__ __launch_bounds__(256) void spmm_csr_kernel(
    const float4* __restrict__ t4,     // [N*128]
    const float* __restrict__ pval,
    const int* __restrict__ pcol,
    const int* __restrict__ row_ptr,
    float* __restrict__ out,
    int final_layout)                  // 0: out [n][b][64]; 1: out [b][n][64]
{
    const int r = (blockIdx.x * 256 + threadIdx.x) >> 6;
    const int lane = threadIdx.x & 63;
    if (r >= GCN_N) return;

    const int beg = row_ptr[r];
    const int end = row_ptr[r + 1];

    float4 a0 = make_float4(0.f, 0.f, 0.f, 0.f);
    float4 a1 = make_float4(0.f, 0.f, 0.f, 0.f);

#pragma unroll 2
    for (int j = beg; j < end; ++j) {
        const float v = pval[j];                    // broadcast
        const int c = pcol[j];                      // broadcast
        const float4* tp = t4 + (size_t)c * 128 + lane;
        float4 x0 = tp[0];
        float4 x1 = tp[64];
        a0.x += v * x0.x; a0.y += v * x0.y; a0.z += v * x0.z; a0.w += v * x0.w;
        a1.x += v * x1.x; a1.y += v * x1.y; a1.z += v * x1.z; a1.w += v * x1.w;
    }

    if (!final_layout) {
        float4* o4 = reinterpret_cast<float4*>(out) + (size_t)r * 128 + lane;
        o4[0] = a0;
        o4[64] = a1;
    } else {
        const int b0 = lane >> 4;
        const int d0 = (lane & 15) * 4;
        float4* o0 = reinterpret_cast<float4*>(out + ((size_t)b0 * GCN_N + r) * 64 + d0);
        float4* o1 = reinterpret_cast<float4*>(out + ((size_t)(b0 + 4) * GCN_N + r) * 64 + d0);
        *o0 = a0;
        *o1 = a1;
    }
}

extern "C" void kernel_launch(void* const* d_in, const int* in_sizes, int n_in,
                              void* d_out, int out_size, void* d_ws, size_t ws_size,
                              hipStream_t stream) {
    const float* x    = (const float*)d_in[0];
    const float* W0   = (const float*)d_in[1];
    const float* W1   = (const float*)d_in[2];
    const float* W2   = (const float*)d_in[3];
    const float* vals = (const float*)d_in[4];
    const int*   rows = (const int*)d_in[5];
    const int*   cols = (const int*)d_in[6];
    float* out = (float*)d_out;

    const size_t t_bytes = (size_t)GCN_BN * GCN_D * sizeof(float);   // 20,480,000

    char* ws = (char*)d_ws;
    float* t       = (float*)ws;
    size_t off = t_bytes;
    int*   row_ptr = (int*)(ws + off); off += ((GCN_N + 1) * 4 + 255) / 256 * 256;
    int*   cur     = (int*)(ws + off); off += (GCN_N * 4 + 255) / 256 * 256;
    int*   cnt     = (int*)(ws + off); off += (GCN_N * 4 + 255) / 256 * 256;
    float* pval    = (float*)(ws + off); off += GCN_E * 4;
    int*   pcol    = (int*)(ws + off); off += GCN_E * 4;

    const int gemm_grid = 1280;                       // 5120 waves, ~4 groups each
    const int edge_grid = (GCN_E + 255) / 256;        // 625
    const int spmm_grid = (GCN_N * 64 + 255) / 256;   // 2500 (wave per row)

    // Build CSR once; reused by all 3 layers.
    hipMemsetAsync(cnt, 0, GCN_N * sizeof(int), stream);
    hist_kernel<<<edge_grid, 256, 0, stream>>>(rows, cnt, GCN_E);
    scan_kernel<<<1, 256, 0, stream>>>(cnt, row_ptr, cur);
    scatter_kernel<<<edge_grid, 256, 0, stream>>>(vals, rows, cols, cur, pval, pcol, GCN_E);

    const float4* t4 = (const float4*)t;

    // layer 1: x is [b][n][64] -> permuted read; t, h in [n][b][64]
    gemm_relu_kernel<<<gemm_grid, 256, 0, stream>>>(x, W0, t, 1);
    spmm_csr_kernel<<<spmm_grid, 256, 0, stream>>>(t4, pval, pcol, row_ptr, out, 0);

    // layer 2
    gemm_relu_kernel<<<gemm_grid, 256, 0, stream>>>(out, W1, t, 0);
    spmm_csr_kernel<<<spmm_grid, 256, 0, stream>>>(t4, pval, pcol, row_ptr, out, 0);

    // layer 3: final output in [b][n][64]
    gemm_relu_kernel<<<gemm_grid, 256, 0, stream>>>(out, W2, t, 0);
    spmm_csr_kernel<<<spmm_grid, 256, 0, stream>>>(t4, pval, pcol, row_ptr, out, 1);
}

// Round 5
// 295.832 us; speedup vs baseline: 3.2447x; 1.1529x over previous
//
#include <hip/hip_runtime.h>
#include <hip/hip_bf16.h>

// GCN block: 3 x { t = relu(h @ W^T); h' = A_coo @ t (per batch) }
// B=8, N=10000, D=64, E=160000.
//
// Round 5:
//  - gemm_relu_lds: block stages a 64-row x 64-col h tile (16KB) into LDS with
//    coalesced dwordx4 loads, then each wave computes 16 rows via wave-uniform
//    ds_read_b128 broadcasts (W stays in 64 VGPRs per lane, lane = feature).
//    Round 4 was latency-bound on broadcast GLOBAL loads (VALUBusy 19%,
//    56us vs ~4.3us VALU floor). LDS broadcast reads are ~60cy and pipeline.
//  - SpMM / CSR build unchanged from round 4 (SpMM ~ L2/L3 gather-BW bound).

#define GCN_B 8
#define GCN_N 10000
#define GCN_D 64
#define GCN_E 160000
#define GCN_BN (GCN_B * GCN_N)

// ---------------- GEMM + ReLU (LDS-staged) ----------------
// out rows are [n][b] flat: rid = n*8 + b. If permute_in, input row for flat
// id g is b*N+n (layer 1 reads x in [b][n][64]); else input is [n][b] flat.
__global__ __launch_bounds__(256) void gemm_relu_lds(
    const float* __restrict__ h,
    const float* __restrict__ W,   // [64,64]; out[f] = sum_d h[d]*W[f*64+d]
    float* __restrict__ t,         // [N][B][64] flat
    int permute_in)
{
    __shared__ float hs[64 * 64];  // 16 KB: 64 rows x 64 floats

    const int tid = threadIdx.x;
    const int f = tid & 63;        // lane = output feature
    const int w = tid >> 6;        // wave id (0..3)
    const int g0 = blockIdx.x * 64;

    // Stage 64 rows (1024 float4) cooperatively; q = k*256 + tid.
    float4* hs4w = reinterpret_cast<float4*>(hs);
#pragma unroll
    for (int k = 0; k < 4; ++k) {
        int q = k * 256 + tid;
        int row = q >> 4;          // 0..63
        int c4 = q & 15;
        int g = g0 + row;
        const float4* src;
        if (permute_in) {
            int n = g >> 3, b = g & 7;
            src = reinterpret_cast<const float4*>(h + ((size_t)b * GCN_N + n) * 64) + c4;
        } else {
            src = reinterpret_cast<const float4*>(h + (size_t)g * 64) + c4;
        }
        hs4w[q] = *src;
    }

    // W row f into registers (overlaps with the barrier wait).
    float4 wr[16];
    const float4* W4 = reinterpret_cast<const float4*>(W);
#pragma unroll
    for (int i = 0; i < 16; ++i) wr[i] = W4[f * 16 + i];

    __syncthreads();

    // Each wave computes 16 rows from LDS (wave-uniform b128 broadcasts).
    const float4* hs4 = reinterpret_cast<const float4*>(hs);
#pragma unroll 4
    for (int rr = 0; rr < 16; ++rr) {
        const int row = w * 16 + rr;
        float acc = 0.f;
#pragma unroll
        for (int i = 0; i < 16; ++i) {
            float4 v = hs4[row * 16 + i];
            acc += v.x * wr[i].x + v.y * wr[i].y + v.z * wr[i].z + v.w * wr[i].w;
        }
        t[(size_t)(g0 + row) * 64 + f] = fmaxf(acc, 0.0f);
    }
}

// ---------------- CSR build ----------------
__global__ __launch_bounds__(256) void hist_kernel(
    const int* __restrict__ rows, int* __restrict__ cnt, int E)
{
    int e = blockIdx.x * 256 + threadIdx.x;
    if (e < E) atomicAdd(&cnt[rows[e]], 1);
}

__global__ __launch_bounds__(256) void scan_kernel(
    const int* __restrict__ cnt, int* __restrict__ row_ptr, int* __restrict__ cur)
{
    __shared__ int part[256];
    const int tid = threadIdx.x;
    const int per = (GCN_N + 255) / 256;   // 40
    const int base = tid * per;

    int s = 0;
    for (int i = 0; i < per; ++i) {
        int idx = base + i;
        if (idx < GCN_N) s += cnt[idx];
    }
    part[tid] = s;
    __syncthreads();
    for (int off = 1; off < 256; off <<= 1) {
        int add = (tid >= off) ? part[tid - off] : 0;
        __syncthreads();
        part[tid] += add;
        __syncthreads();
    }
    int run = part[tid] - s;
    for (int i = 0; i < per; ++i) {
        int idx = base + i;
        if (idx < GCN_N) {
            row_ptr[idx] = run;
            cur[idx] = run;
            run += cnt[idx];
        }
    }
    if (tid == 0) row_ptr[GCN_N] = GCN_E;
}

__global__ __launch_bounds__(256) void scatter_kernel(
    const float* __restrict__ vals, const int* __restrict__ rows,
    const int* __restrict__ cols, int* __restrict__ cur,
    float* __restrict__ pval, int* __restrict__ pcol, int E)
{
    int e = blockIdx.x * 256 + threadIdx.x;
    if (e >= E) return;
    int pos = atomicAdd(&cur[rows[e]], 1);
    pval[pos] = vals[e];
    pcol[pos] = cols[e];
}

// ---------------- CSR SpMM (gather, no atomics) ----------------
// t is [N][B*64] = [N][512] floats = [N][128] float4. Lane holds float4
// chunks q=lane and q=64+lane of the 512-float row: b = q>>4, d = (q&15)*4.
__global__ __launch_bounds__(256) void spmm_csr_kernel(
    const float4* __restrict__ t4,     // [N*128]
    const float* __restrict__ pval,
    const int* __restrict__ pcol,
    const int* __restrict__ row_ptr,
    float* __restrict__ out,
    int final_layout)                  // 0: out [n][b][64]; 1: out [b][n][64]
{
    const int r = (blockIdx.x * 256 + threadIdx.x) >> 6;
    const int lane = threadIdx.x & 63;
    if (r >= GCN_N) return;

    const int beg = row_ptr[r];
    const int end = row_ptr[r + 1];

    float4 a0 = make_float4(0.f, 0.f, 0.f, 0.f);
    float4 a1 = make_float4(0.f, 0.f, 0.f, 0.f);

#pragma unroll 2
    for (int j = beg; j < end; ++j) {
        const float v = pval[j];                    // broadcast
        const int c = pcol[j];                      // broadcast
        const float4* tp = t4 + (size_t)c * 128 + lane;
        float4 x0 = tp[0];
        float4 x1 = tp[64];
        a0.x += v * x0.x; a0.y += v * x0.y; a0.z += v * x0.z; a0.w += v * x0.w;
        a1.x += v * x1.x; a1.y += v * x1.y; a1.z += v * x1.z; a1.w += v * x1.w;
    }

    if (!final_layout) {
        float4* o4 = reinterpret_cast<float4*>(out) + (size_t)r * 128 + lane;
        o4[0] = a0;
        o4[64] = a1;
    } else {
        const int b0 = lane >> 4;
        const int d0 = (lane & 15) * 4;
        float4* o0 = reinterpret_cast<float4*>(out + ((size_t)b0 * GCN_N + r) * 64 + d0);
        float4* o1 = reinterpret_cast<float4*>(out + ((size_t)(b0 + 4) * GCN_N + r) * 64 + d0);
        *o0 = a0;
        *o1 = a1;
    }
}

extern "C" void kernel_launch(void* const* d_in, const int* in_sizes, int n_in,
                              void* d_out, int out_size, void* d_ws, size_t ws_size,
                              hipStream_t stream) {
    const float* x    = (const float*)d_in[0];
    const float* W0   = (const float*)d_in[1];
    const float* W1   = (const float*)d_in[2];
    const float* W2   = (const float*)d_in[3];
    const float* vals = (const float*)d_in[4];
    const int*   rows = (const int*)d_in[5];
    const int*   cols = (const int*)d_in[6];
    float* out = (float*)d_out;

    const size_t t_bytes = (size_t)GCN_BN * GCN_D * sizeof(float);   // 20,480,000

    char* ws = (char*)d_ws;
    float* t       = (float*)ws;
    size_t off = t_bytes;
    int*   row_ptr = (int*)(ws + off); off += ((GCN_N + 1) * 4 + 255) / 256 * 256;
    int*   cur     = (int*)(ws + off); off += (GCN_N * 4 + 255) / 256 * 256;
    int*   cnt     = (int*)(ws + off); off += (GCN_N * 4 + 255) / 256 * 256;
    float* pval    = (float*)(ws + off); off += GCN_E * 4;
    int*   pcol    = (int*)(ws + off); off += GCN_E * 4;

    const int gemm_grid = GCN_BN / 64;                // 1250 tiles, 1 per block
    const int edge_grid = (GCN_E + 255) / 256;        // 625
    const int spmm_grid = (GCN_N * 64 + 255) / 256;   // 2500 (wave per row)

    // Build CSR once; reused by all 3 layers.
    hipMemsetAsync(cnt, 0, GCN_N * sizeof(int), stream);
    hist_kernel<<<edge_grid, 256, 0, stream>>>(rows, cnt, GCN_E);
    scan_kernel<<<1, 256, 0, stream>>>(cnt, row_ptr, cur);
    scatter_kernel<<<edge_grid, 256, 0, stream>>>(vals, rows, cols, cur, pval, pcol, GCN_E);

    const float4* t4 = (const float4*)t;

    // layer 1: x is [b][n][64] -> permuted read; t, h in [n][b][64]
    gemm_relu_lds<<<gemm_grid, 256, 0, stream>>>(x, W0, t, 1);
    spmm_csr_kernel<<<spmm_grid, 256, 0, stream>>>(t4, pval, pcol, row_ptr, out, 0);

    // layer 2
    gemm_relu_lds<<<gemm_grid, 256, 0, stream>>>(out, W1, t, 0);
    spmm_csr_kernel<<<spmm_grid, 256, 0, stream>>>(t4, pval, pcol, row_ptr, out, 0);

    // layer 3: final output in [b][n][64]
    gemm_relu_lds<<<gemm_grid, 256, 0, stream>>>(out, W2, t, 0);
    spmm_csr_kernel<<<spmm_grid, 256, 0, stream>>>(t4, pval, pcol, row_ptr, out, 1);
}

// Round 6
// 209.903 us; speedup vs baseline: 4.5731x; 1.4094x over previous
//
#include <hip/hip_runtime.h>
#include <hip/hip_bf16.h>

// GCN block: 3 x { t = relu(h @ W^T); h' = A_coo @ t (per sample) }
// B=8, N=10000, D=64, E=160000.
//
// Round 6:
//  - t stored as bf16 [n][b][64] (10.24 MB). Round-5 SpMM was HBM-BW-bound:
//    133 MB fetch/dispatch (t re-fetched ~6.5x across the 8 XCD-private L2s).
//    bf16 halves the gather bytes; one dwordx4 per lane per edge (8 bf16),
//    shift/mask unpack, f32 accumulate, f32 output. absmax headroom 2.0/20.48.
//  - gemm_relu_lds unchanged except bf16 stores (attribution-clean).
//  - scan_kernel: cnt staged through LDS; coalesced global reads/writes
//    (was stride-40 uncoalesced from a single block).

#define GCN_B 8
#define GCN_N 10000
#define GCN_D 64
#define GCN_E 160000
#define GCN_BN (GCN_B * GCN_N)

// ---------------- GEMM + ReLU (LDS-staged, bf16 out) ----------------
// out rows are [n][b] flat: rid = n*8 + b. If permute_in, input row for flat
// id g is b*N+n (layer 1 reads x in [b][n][64]); else input is [n][b] flat.
__global__ __launch_bounds__(256) void gemm_relu_lds(
    const float* __restrict__ h,
    const float* __restrict__ W,        // [64,64]; out[f] = sum_d h[d]*W[f*64+d]
    __hip_bfloat16* __restrict__ t,     // [N][B][64] bf16 flat
    int permute_in)
{
    __shared__ float hs[64 * 64];  // 16 KB: 64 rows x 64 floats

    const int tid = threadIdx.x;
    const int f = tid & 63;        // lane = output feature
    const int w = tid >> 6;        // wave id (0..3)
    const int g0 = blockIdx.x * 64;

    // Stage 64 rows (1024 float4) cooperatively.
    float4* hs4w = reinterpret_cast<float4*>(hs);
#pragma unroll
    for (int k = 0; k < 4; ++k) {
        int q = k * 256 + tid;
        int row = q >> 4;          // 0..63
        int c4 = q & 15;
        int g = g0 + row;
        const float4* src;
        if (permute_in) {
            int n = g >> 3, b = g & 7;
            src = reinterpret_cast<const float4*>(h + ((size_t)b * GCN_N + n) * 64) + c4;
        } else {
            src = reinterpret_cast<const float4*>(h + (size_t)g * 64) + c4;
        }
        hs4w[q] = *src;
    }

    // W row f into registers (overlaps with the barrier wait).
    float4 wr[16];
    const float4* W4 = reinterpret_cast<const float4*>(W);
#pragma unroll
    for (int i = 0; i < 16; ++i) wr[i] = W4[f * 16 + i];

    __syncthreads();

    const float4* hs4 = reinterpret_cast<const float4*>(hs);
#pragma unroll 4
    for (int rr = 0; rr < 16; ++rr) {
        const int row = w * 16 + rr;
        float acc = 0.f;
#pragma unroll
        for (int i = 0; i < 16; ++i) {
            float4 v = hs4[row * 16 + i];
            acc += v.x * wr[i].x + v.y * wr[i].y + v.z * wr[i].z + v.w * wr[i].w;
        }
        t[(size_t)(g0 + row) * 64 + f] = __float2bfloat16(fmaxf(acc, 0.0f));
    }
}

// ---------------- CSR build ----------------
__global__ __launch_bounds__(256) void hist_kernel(
    const int* __restrict__ rows, int* __restrict__ cnt, int E)
{
    int e = blockIdx.x * 256 + threadIdx.x;
    if (e < E) atomicAdd(&cnt[rows[e]], 1);
}

__global__ __launch_bounds__(256) void scan_kernel(
    const int* __restrict__ cnt, int* __restrict__ row_ptr, int* __restrict__ cur)
{
    __shared__ int sc[GCN_N];      // 40 KB
    __shared__ int part[256];
    const int tid = threadIdx.x;

    for (int i = tid; i < GCN_N; i += 256) sc[i] = cnt[i];   // coalesced
    __syncthreads();

    const int per = (GCN_N + 255) / 256;   // 40
    const int base = tid * per;
    int s = 0;
    for (int i = 0; i < per; ++i) {
        int idx = base + i;
        if (idx < GCN_N) s += sc[idx];
    }
    part[tid] = s;
    __syncthreads();
    for (int off = 1; off < 256; off <<= 1) {
        int add = (tid >= off) ? part[tid - off] : 0;
        __syncthreads();
        part[tid] += add;
        __syncthreads();
    }
    int run = part[tid] - s;               // exclusive prefix of this segment
    for (int i = 0; i < per; ++i) {
        int idx = base + i;
        if (idx < GCN_N) {
            int c = sc[idx];
            sc[idx] = run;                 // in-place: own segment only
            run += c;
        }
    }
    __syncthreads();
    for (int i = tid; i < GCN_N; i += 256) {   // coalesced
        int v = sc[i];
        row_ptr[i] = v;
        cur[i] = v;
    }
    if (tid == 0) row_ptr[GCN_N] = GCN_E;
}

__global__ __launch_bounds__(256) void scatter_kernel(
    const float* __restrict__ vals, const int* __restrict__ rows,
    const int* __restrict__ cols, int* __restrict__ cur,
    float* __restrict__ pval, int* __restrict__ pcol, int E)
{
    int e = blockIdx.x * 256 + threadIdx.x;
    if (e >= E) return;
    int pos = atomicAdd(&cur[rows[e]], 1);
    pval[pos] = vals[e];
    pcol[pos] = cols[e];
}

// ---------------- CSR SpMM (bf16 gather, f32 accumulate) ----------------
// t is [N][512] bf16 = [N][64] uint4. Lane holds elements [lane*8, lane*8+8)
// of the 512-element row: b = lane>>3, d0 = (lane&7)*8.
__global__ __launch_bounds__(256) void spmm_csr_bf16(
    const uint4* __restrict__ t4,      // [N*64]
    const float* __restrict__ pval,
    const int* __restrict__ pcol,
    const int* __restrict__ row_ptr,
    float* __restrict__ out,
    int final_layout)                  // 0: out [n][b][64]; 1: out [b][n][64]
{
    const int r = (blockIdx.x * 256 + threadIdx.x) >> 6;
    const int lane = threadIdx.x & 63;
    if (r >= GCN_N) return;

    const int beg = row_ptr[r];
    const int end = row_ptr[r + 1];

    float a[8];
#pragma unroll
    for (int i = 0; i < 8; ++i) a[i] = 0.f;

#pragma unroll 4
    for (int j = beg; j < end; ++j) {
        const float v = pval[j];                  // broadcast
        const int c = pcol[j];                    // broadcast
        uint4 u = t4[(size_t)c * 64 + lane];      // coalesced 1KB row gather
        a[0] += v * __uint_as_float(u.x << 16);
        a[1] += v * __uint_as_float(u.x & 0xffff0000u);
        a[2] += v * __uint_as_float(u.y << 16);
        a[3] += v * __uint_as_float(u.y & 0xffff0000u);
        a[4] += v * __uint_as_float(u.z << 16);
        a[5] += v * __uint_as_float(u.z & 0xffff0000u);
        a[6] += v * __uint_as_float(u.w << 16);
        a[7] += v * __uint_as_float(u.w & 0xffff0000u);
    }

    const int b = lane >> 3;
    const int d0 = (lane & 7) * 8;
    float* op;
    if (!final_layout) op = out + (size_t)r * 512 + b * 64 + d0;
    else               op = out + ((size_t)b * GCN_N + r) * 64 + d0;
    *reinterpret_cast<float4*>(op)     = make_float4(a[0], a[1], a[2], a[3]);
    *reinterpret_cast<float4*>(op + 4) = make_float4(a[4], a[5], a[6], a[7]);
}

extern "C" void kernel_launch(void* const* d_in, const int* in_sizes, int n_in,
                              void* d_out, int out_size, void* d_ws, size_t ws_size,
                              hipStream_t stream) {
    const float* x    = (const float*)d_in[0];
    const float* W0   = (const float*)d_in[1];
    const float* W1   = (const float*)d_in[2];
    const float* W2   = (const float*)d_in[3];
    const float* vals = (const float*)d_in[4];
    const int*   rows = (const int*)d_in[5];
    const int*   cols = (const int*)d_in[6];
    float* out = (float*)d_out;

    const size_t t_bytes = (size_t)GCN_BN * GCN_D * sizeof(__hip_bfloat16); // 10,240,000

    char* ws = (char*)d_ws;
    __hip_bfloat16* t = (__hip_bfloat16*)ws;
    size_t off = (t_bytes + 255) / 256 * 256;
    int*   row_ptr = (int*)(ws + off); off += ((GCN_N + 1) * 4 + 255) / 256 * 256;
    int*   cur     = (int*)(ws + off); off += (GCN_N * 4 + 255) / 256 * 256;
    int*   cnt     = (int*)(ws + off); off += (GCN_N * 4 + 255) / 256 * 256;
    float* pval    = (float*)(ws + off); off += GCN_E * 4;
    int*   pcol    = (int*)(ws + off); off += GCN_E * 4;

    const int gemm_grid = GCN_BN / 64;                // 1250 tiles
    const int edge_grid = (GCN_E + 255) / 256;        // 625
    const int spmm_grid = (GCN_N * 64 + 255) / 256;   // 2500 (wave per row)

    // Build CSR once; reused by all 3 layers.
    hipMemsetAsync(cnt, 0, GCN_N * sizeof(int), stream);
    hist_kernel<<<edge_grid, 256, 0, stream>>>(rows, cnt, GCN_E);
    scan_kernel<<<1, 256, 0, stream>>>(cnt, row_ptr, cur);
    scatter_kernel<<<edge_grid, 256, 0, stream>>>(vals, rows, cols, cur, pval, pcol, GCN_E);

    const uint4* t4 = (const uint4*)t;

    // layer 1: x is [b][n][64] -> permuted read; intermediates in [n][b][64]
    gemm_relu_lds<<<gemm_grid, 256, 0, stream>>>(x, W0, t, 1);
    spmm_csr_bf16<<<spmm_grid, 256, 0, stream>>>(t4, pval, pcol, row_ptr, out, 0);

    // layer 2
    gemm_relu_lds<<<gemm_grid, 256, 0, stream>>>(out, W1, t, 0);
    spmm_csr_bf16<<<spmm_grid, 256, 0, stream>>>(t4, pval, pcol, row_ptr, out, 0);

    // layer 3: final output in [b][n][64]
    gemm_relu_lds<<<gemm_grid, 256, 0, stream>>>(out, W2, t, 0);
    spmm_csr_bf16<<<spmm_grid, 256, 0, stream>>>(t4, pval, pcol, row_ptr, out, 1);
}